// Round 15
// baseline (259.460 us; speedup 1.0000x reference)
//
#include <hip/hip_runtime.h>

#define B_   2
#define S_   2048
#define D_   1024
#define H_   16
#define DK_  64
#define DFF_ 4096
#define NT_  (B_*S_)   // 4096 tokens
#define QS_  3072      // fused QKV row stride

using u16 = unsigned short;
typedef __attribute__((ext_vector_type(8))) short bf16x8;
typedef __attribute__((ext_vector_type(4))) float f32x4;
typedef __attribute__((ext_vector_type(4))) u16  u16x4;

__device__ __forceinline__ float bf2f(u16 h) {
  union { unsigned u; float f; } c; c.u = ((unsigned)h) << 16; return c.f;
}
__device__ __forceinline__ u16 f2bf(float f) {
  union { float f; unsigned u; } c; c.f = f;
  unsigned u = c.u;
  return (u16)((u + 0x7fffu + ((u >> 16) & 1u)) >> 16);   // RNE
}
__device__ __forceinline__ u16 f2bf_up(float f) {          // round-half-up, 2 VALU ops
  union { float f; unsigned u; } c; c.f = f;
  return (u16)((c.u + 0x8000u) >> 16);
}

__device__ __forceinline__ void load_lds16(const void* g, void* l) {
  __builtin_amdgcn_global_load_lds(
      (const __attribute__((address_space(1))) unsigned int*)g,
      (__attribute__((address_space(3))) unsigned int*)l, 16, 0, 0);
}

__device__ __forceinline__ void store_out(u16* p, float v)   { *p = f2bf(v); }
__device__ __forceinline__ void store_out(float* p, float v) { *p = v; }

// ---------------------------------------------------------------- LayerNorm
__global__ __launch_bounds__(256) void ln_kernel(
    const float* __restrict__ x, const float* __restrict__ g,
    const float* __restrict__ bt, u16* __restrict__ o)
{
  const int row = blockIdx.x, t = threadIdx.x;
  const float4 xv = *(const float4*)(x + (size_t)row * D_ + t * 4);
  float f[4] = {xv.x, xv.y, xv.z, xv.w};
  float sum = f[0] + f[1] + f[2] + f[3];
  float sq  = f[0]*f[0] + f[1]*f[1] + f[2]*f[2] + f[3]*f[3];
#pragma unroll
  for (int d = 32; d >= 1; d >>= 1) {
    sum += __shfl_down(sum, d);
    sq  += __shfl_down(sq, d);
  }
  __shared__ float red[8];
  const int lane = t & 63, wid = t >> 6;
  if (lane == 0) { red[wid] = sum; red[wid + 4] = sq; }
  __syncthreads();
  sum = red[0] + red[1] + red[2] + red[3];
  sq  = red[4] + red[5] + red[6] + red[7];
  const float mu   = sum * (1.0f / D_);
  const float var  = sq * (1.0f / D_) - mu * mu;
  const float rstd = rsqrtf(var + 1e-5f);
  const float4 gv = *(const float4*)(g  + t * 4);
  const float4 bv = *(const float4*)(bt + t * 4);
  u16x4 ov;
  ov[0] = f2bf((f[0] - mu) * rstd * gv.x + bv.x);
  ov[1] = f2bf((f[1] - mu) * rstd * gv.y + bv.y);
  ov[2] = f2bf((f[2] - mu) * rstd * gv.z + bv.z);
  ov[3] = f2bf((f[3] - mu) * rstd * gv.w + bv.w);
  *(u16x4*)(o + (size_t)row * D_ + t * 4) = ov;
}

// ------------------------------------------------- tiled transpose f32->bf16
__global__ __launch_bounds__(256) void transpose_h(
    const float* __restrict__ in, u16* __restrict__ out, int R, int C)
{
  __shared__ float tile[32][33];
  const int z = blockIdx.z;
  const float* ip = in  + (size_t)z * R * C;
  u16*         op = out + (size_t)z * R * C;
  const int c0 = blockIdx.x * 32, r0 = blockIdx.y * 32;
  const int tx = threadIdx.x & 31, ty = threadIdx.x >> 5;
#pragma unroll
  for (int i = 0; i < 32; i += 8)
    tile[ty + i][tx] = ip[(size_t)(r0 + ty + i) * C + c0 + tx];
  __syncthreads();
#pragma unroll
  for (int i = 0; i < 32; i += 8)
    op[(size_t)(c0 + ty + i) * R + r0 + tx] = f2bf(tile[tx][ty + i]);
}

// ------------------------------------------ fused Wq/Wk/Wv per-head transpose
// Wq folded by 0.125 (exact exponent shift in bf16) so QK^T is pre-scaled.
__global__ __launch_bounds__(256) void transpose_qkv(
    const float* __restrict__ Wq, const float* __restrict__ Wk,
    const float* __restrict__ Wv, u16* __restrict__ out)
{
  __shared__ float tile[32][33];
  const int z = blockIdx.z;            // which*16 + h
  const int which = z >> 4, h = z & 15;
  const float* ip = (which == 0 ? Wq : which == 1 ? Wk : Wv) + (size_t)h * 1024 * 64;
  u16* op = out + ((size_t)which * 1024 + h * 64) * 1024;
  const float sc = (which == 0) ? 0.125f : 1.0f;
  const int c0 = blockIdx.x * 32, r0 = blockIdx.y * 32;
  const int tx = threadIdx.x & 31, ty = threadIdx.x >> 5;
#pragma unroll
  for (int i = 0; i < 32; i += 8)
    tile[ty + i][tx] = ip[(size_t)(r0 + ty + i) * 64 + c0 + tx];
  __syncthreads();
#pragma unroll
  for (int i = 0; i < 32; i += 8)
    op[(size_t)(c0 + ty + i) * 1024 + r0 + tx] = f2bf(tile[tx][ty + i] * sc);
}

// --------------- pack K (straight, per head) + transpose V (per head)
// kt[b*H+h][tok][64]  (K tiles contiguous 8KB), vt[b*H+h][dk][tok]
__global__ __launch_bounds__(256) void pack_kv(
    const u16* __restrict__ qkv, u16* __restrict__ kt, u16* __restrict__ vt)
{
  __shared__ u16 tile[32][72];       // 16B-aligned rows (144B stride)
  const int z = blockIdx.y;          // b*H + h
  const int b = z >> 4, h = z & 15;
  const int t0 = blockIdx.x * 32;
  const int tid = threadIdx.x;
  const int row = tid >> 3, sub = tid & 7;

  const u16* src = qkv + (size_t)(b * S_ + t0 + row) * QS_ + h * DK_ + sub * 8;
  // K: straight copy into packed layout
  *(bf16x8*)(kt + ((size_t)z * S_ + t0 + row) * 64 + sub * 8) =
      *(const bf16x8*)(src + 1024);
  // V: stage tile for transpose
  *(bf16x8*)&tile[row][sub * 8] = *(const bf16x8*)(src + 2048);
  __syncthreads();

  const int d = tid >> 2, tc = (tid & 3) * 8;
  bf16x8 val;
#pragma unroll
  for (int j = 0; j < 8; ++j) val[j] = (short)tile[tc + j][d];
  *(bf16x8*)(vt + ((size_t)z * 64 + d) * S_ + t0 + tc) = val;
}

// --------------------------------------------------- GEMM 256x256 counted-vmcnt
// 512 thr / 8 waves (2M x 4N), BK=32, 4 LDS buffers, prefetch depth 3 K-tiles.
// ONE barrier per K-tile; counted vmcnt(8); st_16x32-style swizzle.
template <typename OT, int KK>
__global__ __launch_bounds__(512, 1) void gemm256(
    const u16* __restrict__ A, const u16* __restrict__ Bt,
    const float* __restrict__ bias, const float* __restrict__ biasB,
    const float* __restrict__ biasC, OT* __restrict__ C,
    int M, int N, int do_relu)
{
  constexpr int NK = KK / 32;
  __shared__ u16 lA[4][256 * 32];   // 64KB
  __shared__ u16 lB[4][256 * 32];   // 64KB
  const int tid = threadIdx.x, lane = tid & 63, wid = tid >> 6;
  const int wr = wid >> 2, wc = wid & 3;

  const int nbx = gridDim.x;
  int bid = blockIdx.y * nbx + blockIdx.x;
  const int cpx = (nbx * gridDim.y) >> 3;
  bid = (bid & 7) * cpx + (bid >> 3);
  const int row0 = (bid / nbx) * 256, col0 = (bid % nbx) * 256;

  const int c0 = tid,       sr0 = c0 >> 2, q0 = ((c0 & 3) ^ (((sr0 >> 3) & 1) << 1)) * 8;
  const int c1 = tid + 512, sr1 = c1 >> 2, q1 = ((c1 & 3) ^ (((sr1 >> 3) & 1) << 1)) * 8;
  const u16* As0 = A  + (size_t)(row0 + sr0) * KK + q0;
  const u16* As1 = A  + (size_t)(row0 + sr1) * KK + q1;
  const u16* Bs0 = Bt + (size_t)(col0 + sr0) * KK + q0;
  const u16* Bs1 = Bt + (size_t)(col0 + sr1) * KK + q1;

  f32x4 acc[8][4] = {};
  const int lrow = lane & 15, kcol = (lane >> 4) * 8;

#pragma unroll
  for (int t = 0; t < 3; ++t) {
    load_lds16(As0 + t * 32, &lA[t][c0 * 8]);
    load_lds16(Bs0 + t * 32, &lB[t][c0 * 8]);
    load_lds16(As1 + t * 32, &lA[t][c1 * 8]);
    load_lds16(Bs1 + t * 32, &lB[t][c1 * 8]);
  }
  asm volatile("s_waitcnt vmcnt(8)" ::: "memory");
  __builtin_amdgcn_sched_barrier(0);
  __builtin_amdgcn_s_barrier();

#pragma unroll 4
  for (int j = 0; j < NK; ++j) {
    const int b = j & 3;
    const u16* la = lA[b];
    const u16* lb = lB[b];
    bf16x8 af[4], bfr[4];

    // ---------------- phase A: m 0..3
#pragma unroll
    for (int m = 0; m < 4; ++m) {
      const int row = wr * 128 + m * 16 + lrow;
      af[m] = *(const bf16x8*)&la[row * 32 + (kcol ^ (((row >> 3) & 1) << 4))];
    }
#pragma unroll
    for (int n = 0; n < 4; ++n) {
      const int row = wc * 64 + n * 16 + lrow;
      bfr[n] = *(const bf16x8*)&lb[row * 32 + (kcol ^ (((row >> 3) & 1) << 4))];
    }
    if (j + 3 < NK) {
      const int bb = (j + 3) & 3;
      load_lds16(As0 + (j + 3) * 32, &lA[bb][c0 * 8]);
      load_lds16(Bs0 + (j + 3) * 32, &lB[bb][c0 * 8]);
    }
    __builtin_amdgcn_s_setprio(1);
#pragma unroll
    for (int m = 0; m < 4; ++m)
#pragma unroll
      for (int n = 0; n < 4; ++n)
        acc[m][n] = __builtin_amdgcn_mfma_f32_16x16x32_bf16(af[m], bfr[n], acc[m][n], 0, 0, 0);
    __builtin_amdgcn_s_setprio(0);

    // ---------------- phase B: m 4..7 (bfr reused; no mid barrier)
#pragma unroll
    for (int m = 0; m < 4; ++m) {
      const int row = wr * 128 + (m + 4) * 16 + lrow;
      af[m] = *(const bf16x8*)&la[row * 32 + (kcol ^ (((row >> 3) & 1) << 4))];
    }
    if (j + 3 < NK) {
      const int bb = (j + 3) & 3;
      load_lds16(As1 + (j + 3) * 32, &lA[bb][c1 * 8]);
      load_lds16(Bs1 + (j + 3) * 32, &lB[bb][c1 * 8]);
    }
    __builtin_amdgcn_s_setprio(1);
#pragma unroll
    for (int m = 0; m < 4; ++m)
#pragma unroll
      for (int n = 0; n < 4; ++n)
        acc[m + 4][n] = __builtin_amdgcn_mfma_f32_16x16x32_bf16(af[m], bfr[n], acc[m + 4][n], 0, 0, 0);
    __builtin_amdgcn_s_setprio(0);
    if (j + 3 < NK)      { asm volatile("s_waitcnt vmcnt(8)" ::: "memory"); }
    else if (j + 2 < NK) { asm volatile("s_waitcnt vmcnt(4)" ::: "memory"); }
    else if (j + 1 < NK) { asm volatile("s_waitcnt vmcnt(0)" ::: "memory"); }
    __builtin_amdgcn_sched_barrier(0);
    __builtin_amdgcn_s_barrier();
  }

#pragma unroll
  for (int m = 0; m < 8; ++m)
#pragma unroll
    for (int n = 0; n < 4; ++n) {
      const int rbase = row0 + wr*128 + m*16 + ((lane >> 4) << 2);
      const int c     = col0 + wc*64 + n*16 + (lane & 15);
      float bv = 0.f;
      if (biasC)      bv = c < 1024 ? bias[c] * 0.125f
                         : (c < 2048 ? biasB[c - 1024] : biasC[c - 2048]);
      else if (bias)  bv = bias[c];
#pragma unroll
      for (int r = 0; r < 4; ++r) {
        float vv = acc[m][n][r] + bv;
        if (do_relu) vv = vv > 0.f ? vv : 0.f;
        store_out(&C[(size_t)(rbase + r) * N + c], vv);
      }
    }
}

// ----------------------------- GEMM 256x256 counted-vmcnt, split-K partial out
template <int KK>
__global__ __launch_bounds__(512, 1) void gemm256pk(
    const u16* __restrict__ A, const u16* __restrict__ Bt,
    u16* __restrict__ P, int M, int N, int Ktot)
{
  constexpr int NK = KK / 32;
  __shared__ u16 lA[4][256 * 32];
  __shared__ u16 lB[4][256 * 32];
  const int tid = threadIdx.x, lane = tid & 63, wid = tid >> 6;
  const int wr = wid >> 2, wc = wid & 3;

  const int nbx = gridDim.x;
  int bid = blockIdx.y * nbx + blockIdx.x;
  const int cpx = (nbx * gridDim.y) >> 3;
  bid = (bid & 7) * cpx + (bid >> 3);
  const int row0 = (bid / nbx) * 256, col0 = (bid % nbx) * 256;
  const int kb = blockIdx.z * KK;

  const int c0 = tid,       sr0 = c0 >> 2, q0 = ((c0 & 3) ^ (((sr0 >> 3) & 1) << 1)) * 8;
  const int c1 = tid + 512, sr1 = c1 >> 2, q1 = ((c1 & 3) ^ (((sr1 >> 3) & 1) << 1)) * 8;
  const u16* As0 = A  + (size_t)(row0 + sr0) * Ktot + kb + q0;
  const u16* As1 = A  + (size_t)(row0 + sr1) * Ktot + kb + q1;
  const u16* Bs0 = Bt + (size_t)(col0 + sr0) * Ktot + kb + q0;
  const u16* Bs1 = Bt + (size_t)(col0 + sr1) * Ktot + kb + q1;

  f32x4 acc[8][4] = {};
  const int lrow = lane & 15, kcol = (lane >> 4) * 8;

#pragma unroll
  for (int t = 0; t < 3; ++t) {
    load_lds16(As0 + t * 32, &lA[t][c0 * 8]);
    load_lds16(Bs0 + t * 32, &lB[t][c0 * 8]);
    load_lds16(As1 + t * 32, &lA[t][c1 * 8]);
    load_lds16(Bs1 + t * 32, &lB[t][c1 * 8]);
  }
  asm volatile("s_waitcnt vmcnt(8)" ::: "memory");
  __builtin_amdgcn_sched_barrier(0);
  __builtin_amdgcn_s_barrier();

#pragma unroll 4
  for (int j = 0; j < NK; ++j) {
    const int b = j & 3;
    const u16* la = lA[b];
    const u16* lb = lB[b];
    bf16x8 af[4], bfr[4];

#pragma unroll
    for (int m = 0; m < 4; ++m) {
      const int row = wr * 128 + m * 16 + lrow;
      af[m] = *(const bf16x8*)&la[row * 32 + (kcol ^ (((row >> 3) & 1) << 4))];
    }
#pragma unroll
    for (int n = 0; n < 4; ++n) {
      const int row = wc * 64 + n * 16 + lrow;
      bfr[n] = *(const bf16x8*)&lb[row * 32 + (kcol ^ (((row >> 3) & 1) << 4))];
    }
    if (j + 3 < NK) {
      const int bb = (j + 3) & 3;
      load_lds16(As0 + (j + 3) * 32, &lA[bb][c0 * 8]);
      load_lds16(Bs0 + (j + 3) * 32, &lB[bb][c0 * 8]);
    }
    __builtin_amdgcn_s_setprio(1);
#pragma unroll
    for (int m = 0; m < 4; ++m)
#pragma unroll
      for (int n = 0; n < 4; ++n)
        acc[m][n] = __builtin_amdgcn_mfma_f32_16x16x32_bf16(af[m], bfr[n], acc[m][n], 0, 0, 0);
    __builtin_amdgcn_s_setprio(0);

#pragma unroll
    for (int m = 0; m < 4; ++m) {
      const int row = wr * 128 + (m + 4) * 16 + lrow;
      af[m] = *(const bf16x8*)&la[row * 32 + (kcol ^ (((row >> 3) & 1) << 4))];
    }
    if (j + 3 < NK) {
      const int bb = (j + 3) & 3;
      load_lds16(As1 + (j + 3) * 32, &lA[bb][c1 * 8]);
      load_lds16(Bs1 + (j + 3) * 32, &lB[bb][c1 * 8]);
    }
    __builtin_amdgcn_s_setprio(1);
#pragma unroll
    for (int m = 0; m < 4; ++m)
#pragma unroll
      for (int n = 0; n < 4; ++n)
        acc[m + 4][n] = __builtin_amdgcn_mfma_f32_16x16x32_bf16(af[m], bfr[n], acc[m + 4][n], 0, 0, 0);
    __builtin_amdgcn_s_setprio(0);
    if (j + 3 < NK)      { asm volatile("s_waitcnt vmcnt(8)" ::: "memory"); }
    else if (j + 2 < NK) { asm volatile("s_waitcnt vmcnt(4)" ::: "memory"); }
    else if (j + 1 < NK) { asm volatile("s_waitcnt vmcnt(0)" ::: "memory"); }
    __builtin_amdgcn_sched_barrier(0);
    __builtin_amdgcn_s_barrier();
  }

  u16* Pz = P + (size_t)blockIdx.z * M * N;
#pragma unroll
  for (int m = 0; m < 8; ++m)
#pragma unroll
    for (int n = 0; n < 4; ++n) {
      const int rbase = row0 + wr*128 + m*16 + ((lane >> 4) << 2);
      const int c     = col0 + wc*64 + n*16 + (lane & 15);
#pragma unroll
      for (int r = 0; r < 4; ++r)
        Pz[(size_t)(rbase + r) * N + c] = f2bf(acc[m][n][r]);
    }
}

// ------------------------------------------- GEMM 128x64, 2-phase dbuf (proven)
template <typename OT>
__global__ __launch_bounds__(256) void gemm_bt64(
    const u16* __restrict__ A, const u16* __restrict__ Bt,
    const float* __restrict__ bias, const float* __restrict__ res,
    OT* __restrict__ C, int M, int N, int K, int do_relu)
{
  __shared__ u16 lA[2][128 * 32];
  __shared__ u16 lB[2][64 * 32];
  const int tid = threadIdx.x, lane = tid & 63, wid = tid >> 6;

  const int nbx = gridDim.x;
  int bid = blockIdx.y * nbx + blockIdx.x;
  const int cpx = (nbx * gridDim.y) >> 3;
  bid = (bid & 7) * cpx + (bid >> 3);
  const int row0 = (bid / nbx) * 128, col0 = (bid % nbx) * 64;

  f32x4 acc[2][4] = {};

  const int cc0 = tid, cc1 = tid + 256;
  const int r0 = cc0 >> 2, s0 = cc0 & 3;
  const int r1 = cc1 >> 2, s1 = cc1 & 3;
  const int ko0 = (s0 ^ ((r0 >> 1) & 3)) * 8;
  const int ko1 = (s1 ^ ((r1 >> 1) & 3)) * 8;

#define GST64(bf, k0)                                                         \
  {                                                                           \
    load_lds16(A  + (size_t)(row0 + r0) * K + (k0) + ko0, &lA[bf][cc0 * 8]);  \
    load_lds16(A  + (size_t)(row0 + r1) * K + (k0) + ko1, &lA[bf][cc1 * 8]);  \
    load_lds16(Bt + (size_t)(col0 + r0) * K + (k0) + ko0, &lB[bf][cc0 * 8]);  \
  }

  const int nk = K >> 5;
  GST64(0, 0);
  int cur = 0;
  for (int t = 0; t < nk; ++t) {
    __syncthreads();
    if (t + 1 < nk) GST64(cur ^ 1, (t + 1) * 32);
    bf16x8 af[2], bfr[4];
#pragma unroll
    for (int m = 0; m < 2; ++m) {
      const int row = wid * 32 + m * 16 + (lane & 15);
      af[m] = *(const bf16x8*)&lA[cur][row * 32 + (((lane >> 4) ^ ((row >> 1) & 3)) * 8)];
    }
#pragma unroll
    for (int n = 0; n < 4; ++n) {
      const int row = n * 16 + (lane & 15);
      bfr[n] = *(const bf16x8*)&lB[cur][row * 32 + (((lane >> 4) ^ ((row >> 1) & 3)) * 8)];
    }
#pragma unroll
    for (int m = 0; m < 2; ++m)
#pragma unroll
      for (int n = 0; n < 4; ++n)
        acc[m][n] = __builtin_amdgcn_mfma_f32_16x16x32_bf16(af[m], bfr[n], acc[m][n], 0, 0, 0);
    cur ^= 1;
  }
#undef GST64

#pragma unroll
  for (int m = 0; m < 2; ++m)
#pragma unroll
    for (int n = 0; n < 4; ++n) {
      const int rbase = row0 + wid*32 + m*16 + ((lane >> 4) << 2);
      const int c     = col0 + n*16 + (lane & 15);
      const float bv  = bias ? bias[c] : 0.f;
#pragma unroll
      for (int r = 0; r < 4; ++r) {
        const int rr = rbase + r;
        float vv = acc[m][n][r] + bv;
        if (res) vv += res[(size_t)rr * N + c];
        if (do_relu) vv = vv > 0.f ? vv : 0.f;
        store_out(&C[(size_t)rr * N + c], vv);
      }
    }
}

// ---------------------------- split-K=4 reduce: out = sum(bf16 partials)+x1+b2
__global__ __launch_bounds__(256) void ffr_reduce4(
    const u16* __restrict__ P, const float* __restrict__ x1,
    const float* __restrict__ b2, float* __restrict__ out)
{
  const size_t i = (size_t)blockIdx.x * 256 + threadIdx.x;   // float4 index
  const size_t M4 = (size_t)NT_ * D_;                        // elems per slab
  const float4 r  = ((const float4*)x1)[i];
  const float4 bb = ((const float4*)b2)[i & 255];
  float o0 = r.x + bb.x, o1 = r.y + bb.y, o2 = r.z + bb.z, o3 = r.w + bb.w;
#pragma unroll
  for (int z = 0; z < 4; ++z) {
    const u16x4 p = *(const u16x4*)(P + z * M4 + i * 4);
    o0 += bf2f(p[0]); o1 += bf2f(p[1]); o2 += bf2f(p[2]); o3 += bf2f(p[3]);
  }
  float4 o; o.x = o0; o.y = o1; o.z = o2; o.w = o3;
  ((float4*)out)[i] = o;
}

// ------------------------------------------------------------ flash attention
// 512 thr / 8 waves, 128 q-rows/block, KVBLK=128 (16 tiles). LDS: lK 16KB
// (single buf) + lV 2x16KB (dbuf) + lP 32KB = 80KB -> 2 blocks/CU.
// Per tile: top sync -> issue V(t+1) -> QK^T(16 MFMA) -> softmax(1 chain/128
// keys) -> lP -> mid sync -> issue K(t+1) (overlaps PV) -> PV+l (20 MFMA).
__global__ __launch_bounds__(512, 4) void attn_kernel(
    const u16* __restrict__ QKV, const u16* __restrict__ Kt,
    const u16* __restrict__ Vt, u16* __restrict__ O)
{
  __shared__ u16 lK[128 * 64];        // [k][dk]
  __shared__ u16 lV[2][64 * 128];     // [dk][k]
  __shared__ u16 lP[128 * 128];       // [q][k]

  const int tid = threadIdx.x, lane = tid & 63, wid = tid >> 6;   // wid 0..7
  const int g  = (blockIdx.x & 7) * 64 + (blockIdx.x >> 3);       // 0..511
  const int qt = g & 15, h = (g >> 4) & 15, b = g >> 8;
  const int z  = b * H_ + h;

  const u16* Qp  = QKV + (size_t)(b * S_ + qt * 128) * QS_ + h * DK_;
  const u16* Kpb = Kt + (size_t)z * S_ * 64;       // packed [tok][64]
  const u16* Vb  = Vt + (size_t)z * DK_ * S_;      // [dk][tok]

  const int hi = lane >> 4;

  bf16x8 qf[2];
  {
    const int qr = wid * 16 + (lane & 15);    // 0..127
    qf[0] = *(const bf16x8*)(Qp + (size_t)qr * QS_ + hi * 8);
    qf[1] = *(const bf16x8*)(Qp + (size_t)qr * QS_ + 32 + hi * 8);
  }

  const bf16x8 vone = {16256,16256,16256,16256,16256,16256,16256,16256}; // bf16 1.0

  // K tile: 128x64 = 1024 chunks; thread c: row=c>>3, sub=c&7 (src inv-swizzled)
#define STAGE_K(kt_)                                                          \
  {                                                                           \
    const u16* Kp = Kpb + (size_t)(kt_) * 128 * 64;                           \
    _Pragma("unroll")                                                         \
    for (int i = 0; i < 2; ++i) {                                             \
      const int c = tid + i * 512, r = c >> 3, sub = c & 7;                   \
      load_lds16(Kp + r * 64 + ((sub ^ (r & 7)) * 8), &lK[c * 8]);            \
    }                                                                         \
  }
  // V tile: 64x128 = 1024 chunks; thread c: row(dk)=c>>4, sub=c&15
#define STAGE_V(bf, kt_)                                                      \
  {                                                                           \
    const u16* Vp = Vb + (size_t)(kt_) * 128;                                 \
    _Pragma("unroll")                                                         \
    for (int i = 0; i < 2; ++i) {                                             \
      const int c = tid + i * 512, r = c >> 4, sub = c & 15;                  \
      load_lds16(Vp + (size_t)r * S_ + ((sub ^ (r & 7)) * 8), &lV[bf][c * 8]); \
    }                                                                         \
  }

  float m_run = -1e30f;
  f32x4 l_acc = {};
  f32x4 o_acc[4] = {};

  STAGE_K(0);
  STAGE_V(0, 0);
  int vcur = 0;

  for (int kt = 0; kt < S_ / 128; ++kt) {
    __syncthreads();                       // K(kt), V(kt) landed; prev PV done
    if (kt + 1 < S_ / 128) STAGE_V(vcur ^ 1, kt + 1);

    // ---- QK^T: s[kf] = D[k][q], k = kf*16 + hi*4 + r, q = lane&15
    f32x4 s[8];
    __builtin_amdgcn_s_setprio(1);
#pragma unroll
    for (int kf = 0; kf < 8; ++kf) {
      const int row = kf * 16 + (lane & 15);
      bf16x8 k0 = *(const bf16x8*)&lK[(row * 64 + hi * 8)      ^ ((row & 7) << 3)];
      bf16x8 k1 = *(const bf16x8*)&lK[(row * 64 + 32 + hi * 8) ^ ((row & 7) << 3)];
      f32x4 sc = {};
      sc = __builtin_amdgcn_mfma_f32_16x16x32_bf16(k0, qf[0], sc, 0, 0, 0);
      sc = __builtin_amdgcn_mfma_f32_16x16x32_bf16(k1, qf[1], sc, 0, 0, 0);
      s[kf] = sc;
    }
    __builtin_amdgcn_s_setprio(0);

    // ---- row max over 128 keys (one chain per tile) + 2-shuffle cross-group
    float pmax = -1e30f;
#pragma unroll
    for (int kf = 0; kf < 8; ++kf) {
      const float t = fmaxf(fmaxf(s[kf][0], s[kf][1]), fmaxf(s[kf][2], s[kf][3]));
      pmax = fmaxf(pmax, t);
    }
    pmax = fmaxf(pmax, __shfl_xor(pmax, 16));
    pmax = fmaxf(pmax, __shfl_xor(pmax, 32));

    // ---- defer-max rescale (THR=8 -> P bounded by e^8)
    const bool grow = pmax > m_run + 8.0f;
    const float mnew = grow ? pmax : m_run;
    if (__any(grow)) {
      const float scale = __expf(m_run - mnew);
#pragma unroll
      for (int r = 0; r < 4; ++r) {
        const float sr = __shfl(scale, hi * 4 + r);
        l_acc[r] *= sr;
#pragma unroll
        for (int nf = 0; nf < 4; ++nf) o_acc[nf][r] *= sr;
      }
    }
    m_run = mnew;

    // ---- P = exp(s - m) -> lP[q][k] (swizzled, 8B packed writes)
    const int prow = wid * 16 + (lane & 15);     // q-row 0..127
#pragma unroll
    for (int kf = 0; kf < 8; ++kf) {
      u16x4 pk;
#pragma unroll
      for (int r = 0; r < 4; ++r) pk[r] = f2bf_up(__expf(s[kf][r] - m_run));
      const int idx = (prow * 128 + kf * 16 + hi * 4) ^ ((prow & 7) << 3);
      *(u16x4*)&lP[idx] = pk;
    }

    __syncthreads();                       // all waves done with lK; lP visible
    if (kt + 1 < S_ / 128) STAGE_K(kt + 1);   // overlaps PV below

    bf16x8 pa[4];
#pragma unroll
    for (int si = 0; si < 4; ++si)
      pa[si] = *(const bf16x8*)&lP[(prow * 128 + si * 32 + hi * 8) ^ ((prow & 7) << 3)];

    __builtin_amdgcn_s_setprio(1);
#pragma unroll
    for (int si = 0; si < 4; ++si)
      l_acc = __builtin_amdgcn_mfma_f32_16x16x32_bf16(pa[si], vone, l_acc, 0, 0, 0);
#pragma unroll
    for (int nf = 0; nf < 4; ++nf) {
      const int vrow = nf * 16 + (lane & 15);
#pragma unroll
      for (int si = 0; si < 4; ++si) {
        bf16x8 v = *(const bf16x8*)&lV[vcur][(vrow * 128 + si * 32 + hi * 8) ^ ((vrow & 7) << 3)];
        o_acc[nf] = __builtin_amdgcn_mfma_f32_16x16x32_bf16(pa[si], v, o_acc[nf], 0, 0, 0);
      }
    }
    __builtin_amdgcn_s_setprio(0);
    vcur ^= 1;
  }

#pragma unroll
  for (int nf = 0; nf < 4; ++nf)
#pragma unroll
    for (int r = 0; r < 4; ++r) {
      const int qrow = qt * 128 + wid * 16 + hi * 4 + r;
      const int col  = h * DK_ + nf * 16 + (lane & 15);
      O[(size_t)(b * S_ + qrow) * D_ + col] = f2bf(o_acc[nf][r] / l_acc[r]);
    }
}

// ------------------------------------------------------------------ launcher
extern "C" void kernel_launch(void* const* d_in, const int* in_sizes, int n_in,
                              void* d_out, int out_size, void* d_ws, size_t ws_size,
                              hipStream_t stream)
{
  const float* x   = (const float*)d_in[0];
  const float* Wq  = (const float*)d_in[1];
  const float* bq  = (const float*)d_in[2];
  const float* Wk  = (const float*)d_in[3];
  const float* bk  = (const float*)d_in[4];
  const float* Wv  = (const float*)d_in[5];
  const float* bv  = (const float*)d_in[6];
  const float* Wo  = (const float*)d_in[7];
  const float* bo  = (const float*)d_in[8];
  const float* W1  = (const float*)d_in[9];
  const float* b1  = (const float*)d_in[10];
  const float* W2  = (const float*)d_in[11];
  const float* b2  = (const float*)d_in[12];
  const float* g1  = (const float*)d_in[13];
  const float* be1 = (const float*)d_in[14];
  const float* g2  = (const float*)d_in[15];
  const float* be2 = (const float*)d_in[16];
  float* out = (float*)d_out;

  const size_t MB = 1024 * 1024;
  char* base = (char*)d_ws;
  u16*   xn    = (u16*)(base);             //  8MB bf16 [4096][1024]
  u16*   qkv   = (u16*)(base +  8*MB);     // 24MB bf16 [4096][3072]
  u16*   ctx   = (u16*)(base + 32*MB);     //  8MB bf16 [4096][1024]
  float* x1    = (float*)(base + 40*MB);   // 16MB f32  [4096][1024]
  u16*   vt    = (u16*)(base + 40*MB);     //  8MB bf16 [32][64][2048] (dead before x1)
  u16*   kt    = (u16*)(base + 48*MB);     //  8MB bf16 [32][2048][64] (dead before x1)
  u16*   ff1   = (u16*)(base +  8*MB);     // 32MB bf16 [4096][4096] (reuses qkv+ctx)
  u16*   wqkvT = (u16*)(base + 56*MB);     //  6MB
  u16*   woT   = (u16*)(base + 62*MB);     //  2MB
  u16*   w1T   = (u16*)(base + 64*MB);     //  8MB
  u16*   w2T   = (u16*)(base + 72*MB);     //  8MB
  u16*   pkh   = (u16*)(base + 80*MB);     // 32MB bf16 split-K partials [4][4096][1024]

  const bool splitk = ws_size >= (size_t)112 * MB;

  dim3 blk(256);
  transpose_qkv<<<dim3(2, 32, 48), blk, 0, stream>>>(Wq, Wk, Wv, wqkvT);
  transpose_h<<<dim3(32, 32, 1),  blk, 0, stream>>>(Wo, woT, 1024, 1024);
  transpose_h<<<dim3(128, 32, 1), blk, 0, stream>>>(W1, w1T, 1024, 4096);
  transpose_h<<<dim3(32, 128, 1), blk, 0, stream>>>(W2, w2T, 4096, 1024);

  ln_kernel<<<NT_, blk, 0, stream>>>(x, g1, be1, xn);

  // fused QKV projection via 256x256 counted-vmcnt kernel (192 blocks)
  gemm256<u16, 1024><<<dim3(12, 16), dim3(512), 0, stream>>>(
      xn, wqkvT, bq, bk, bv, qkv, NT_, QS_, 0);

  pack_kv<<<dim3(S_ / 32, B_ * H_), blk, 0, stream>>>(qkv, kt, vt);

  attn_kernel<<<dim3(512), dim3(512), 0, stream>>>(qkv, kt, vt, ctx);

  gemm_bt64<<<dim3(16, 32), blk, 0, stream>>>(ctx, woT, bo, x, x1, NT_, D_, D_, 0);

  ln_kernel<<<NT_, blk, 0, stream>>>(x1, g2, be2, xn);

  // FF1 via 256x256 counted-vmcnt kernel (256 blocks)
  gemm256<u16, 1024><<<dim3(16, 16), dim3(512), 0, stream>>>(
      xn, w1T, b1, (const float*)nullptr, (const float*)nullptr, ff1, NT_, DFF_, 1);

  if (splitk) {
    // FF2 via gemm256 template, split-K=4 (4x64 = 256 blocks, KK=1024)
    gemm256pk<1024><<<dim3(4, 16, 4), dim3(512), 0, stream>>>(
        ff1, w2T, pkh, NT_, D_, DFF_);
    ffr_reduce4<<<dim3(4096), blk, 0, stream>>>(pkh, x1, b2, out);
  } else {
    gemm_bt64<<<dim3(16, 32), blk, 0, stream>>>(ff1, w2T, b2, x1, out, NT_, D_, DFF_, 0);
  }
}

// Round 16
// 254.494 us; speedup vs baseline: 1.0195x; 1.0195x over previous
//
#include <hip/hip_runtime.h>

#define B_   2
#define S_   2048
#define D_   1024
#define H_   16
#define DK_  64
#define DFF_ 4096
#define NT_  (B_*S_)   // 4096 tokens
#define QS_  3072      // fused QKV row stride

using u16 = unsigned short;
typedef __attribute__((ext_vector_type(8))) short bf16x8;
typedef __attribute__((ext_vector_type(4))) float f32x4;
typedef __attribute__((ext_vector_type(4))) u16  u16x4;

__device__ __forceinline__ float bf2f(u16 h) {
  union { unsigned u; float f; } c; c.u = ((unsigned)h) << 16; return c.f;
}
__device__ __forceinline__ u16 f2bf(float f) {
  union { float f; unsigned u; } c; c.f = f;
  unsigned u = c.u;
  return (u16)((u + 0x7fffu + ((u >> 16) & 1u)) >> 16);   // RNE
}
__device__ __forceinline__ u16 f2bf_up(float f) {          // round-half-up, 2 VALU ops
  union { float f; unsigned u; } c; c.f = f;
  return (u16)((c.u + 0x8000u) >> 16);
}

__device__ __forceinline__ void load_lds16(const void* g, void* l) {
  __builtin_amdgcn_global_load_lds(
      (const __attribute__((address_space(1))) unsigned int*)g,
      (__attribute__((address_space(3))) unsigned int*)l, 16, 0, 0);
}

__device__ __forceinline__ void store_out(u16* p, float v)   { *p = f2bf(v); }
__device__ __forceinline__ void store_out(float* p, float v) { *p = v; }

// ---------------------------------------------------------------- LayerNorm
__global__ __launch_bounds__(256) void ln_kernel(
    const float* __restrict__ x, const float* __restrict__ g,
    const float* __restrict__ bt, u16* __restrict__ o)
{
  const int row = blockIdx.x, t = threadIdx.x;
  const float4 xv = *(const float4*)(x + (size_t)row * D_ + t * 4);
  float f[4] = {xv.x, xv.y, xv.z, xv.w};
  float sum = f[0] + f[1] + f[2] + f[3];
  float sq  = f[0]*f[0] + f[1]*f[1] + f[2]*f[2] + f[3]*f[3];
#pragma unroll
  for (int d = 32; d >= 1; d >>= 1) {
    sum += __shfl_down(sum, d);
    sq  += __shfl_down(sq, d);
  }
  __shared__ float red[8];
  const int lane = t & 63, wid = t >> 6;
  if (lane == 0) { red[wid] = sum; red[wid + 4] = sq; }
  __syncthreads();
  sum = red[0] + red[1] + red[2] + red[3];
  sq  = red[4] + red[5] + red[6] + red[7];
  const float mu   = sum * (1.0f / D_);
  const float var  = sq * (1.0f / D_) - mu * mu;
  const float rstd = rsqrtf(var + 1e-5f);
  const float4 gv = *(const float4*)(g  + t * 4);
  const float4 bv = *(const float4*)(bt + t * 4);
  u16x4 ov;
  ov[0] = f2bf((f[0] - mu) * rstd * gv.x + bv.x);
  ov[1] = f2bf((f[1] - mu) * rstd * gv.y + bv.y);
  ov[2] = f2bf((f[2] - mu) * rstd * gv.z + bv.z);
  ov[3] = f2bf((f[3] - mu) * rstd * gv.w + bv.w);
  *(u16x4*)(o + (size_t)row * D_ + t * 4) = ov;
}

// ---------------------- fused Wo/W1/W2 tiled transpose f32->bf16 (one launch)
// linear tile id: [0,1024) Wo(1024x1024), [1024,5120) W1(1024x4096),
// [5120,9216) W2(4096x1024)
__global__ __launch_bounds__(256) void transpose_w(
    const float* __restrict__ Wo, const float* __restrict__ W1,
    const float* __restrict__ W2, u16* __restrict__ woT,
    u16* __restrict__ w1T, u16* __restrict__ w2T)
{
  __shared__ float tile[32][33];
  int t = blockIdx.x;
  const float* in; u16* out; int R, C;
  if (t < 1024)      { in = Wo; out = woT; R = 1024; C = 1024; }
  else if (t < 5120) { in = W1; out = w1T; R = 1024; C = 4096; t -= 1024; }
  else               { in = W2; out = w2T; R = 4096; C = 1024; t -= 5120; }
  const int tilesX = C >> 5;
  const int c0 = (t % tilesX) * 32, r0 = (t / tilesX) * 32;
  const int tx = threadIdx.x & 31, ty = threadIdx.x >> 5;
#pragma unroll
  for (int i = 0; i < 32; i += 8)
    tile[ty + i][tx] = in[(size_t)(r0 + ty + i) * C + c0 + tx];
  __syncthreads();
#pragma unroll
  for (int i = 0; i < 32; i += 8)
    out[(size_t)(c0 + ty + i) * R + r0 + tx] = f2bf(tile[tx][ty + i]);
}

// ------------------------------------------ fused Wq/Wk/Wv per-head transpose
// Wq folded by 0.125 (exact exponent shift in bf16) so QK^T is pre-scaled.
__global__ __launch_bounds__(256) void transpose_qkv(
    const float* __restrict__ Wq, const float* __restrict__ Wk,
    const float* __restrict__ Wv, u16* __restrict__ out)
{
  __shared__ float tile[32][33];
  const int z = blockIdx.z;            // which*16 + h
  const int which = z >> 4, h = z & 15;
  const float* ip = (which == 0 ? Wq : which == 1 ? Wk : Wv) + (size_t)h * 1024 * 64;
  u16* op = out + ((size_t)which * 1024 + h * 64) * 1024;
  const float sc = (which == 0) ? 0.125f : 1.0f;
  const int c0 = blockIdx.x * 32, r0 = blockIdx.y * 32;
  const int tx = threadIdx.x & 31, ty = threadIdx.x >> 5;
#pragma unroll
  for (int i = 0; i < 32; i += 8)
    tile[ty + i][tx] = ip[(size_t)(r0 + ty + i) * 64 + c0 + tx];
  __syncthreads();
#pragma unroll
  for (int i = 0; i < 32; i += 8)
    op[(size_t)(c0 + ty + i) * 1024 + r0 + tx] = f2bf(tile[tx][ty + i] * sc);
}

// --------------- pack K (straight, per head) + transpose V (per head)
// kt[b*H+h][tok][64]  (K tiles contiguous 8KB), vt[b*H+h][dk][tok]
__global__ __launch_bounds__(256) void pack_kv(
    const u16* __restrict__ qkv, u16* __restrict__ kt, u16* __restrict__ vt)
{
  __shared__ u16 tile[32][72];       // 16B-aligned rows (144B stride)
  const int z = blockIdx.y;          // b*H + h
  const int b = z >> 4, h = z & 15;
  const int t0 = blockIdx.x * 32;
  const int tid = threadIdx.x;
  const int row = tid >> 3, sub = tid & 7;

  const u16* src = qkv + (size_t)(b * S_ + t0 + row) * QS_ + h * DK_ + sub * 8;
  *(bf16x8*)(kt + ((size_t)z * S_ + t0 + row) * 64 + sub * 8) =
      *(const bf16x8*)(src + 1024);
  *(bf16x8*)&tile[row][sub * 8] = *(const bf16x8*)(src + 2048);
  __syncthreads();

  const int d = tid >> 2, tc = (tid & 3) * 8;
  bf16x8 val;
#pragma unroll
  for (int j = 0; j < 8; ++j) val[j] = (short)tile[tc + j][d];
  *(bf16x8*)(vt + ((size_t)z * 64 + d) * S_ + t0 + tc) = val;
}

// --------------------------------------------------- GEMM 256x256 counted-vmcnt
// 512 thr / 8 waves (2M x 4N), BK=32, 4 LDS buffers, prefetch depth 3 K-tiles.
// ONE barrier per K-tile; counted vmcnt(8); st_16x32-style swizzle.
template <typename OT, int KK>
__global__ __launch_bounds__(512, 1) void gemm256(
    const u16* __restrict__ A, const u16* __restrict__ Bt,
    const float* __restrict__ bias, const float* __restrict__ biasB,
    const float* __restrict__ biasC, OT* __restrict__ C,
    int M, int N, int do_relu)
{
  constexpr int NK = KK / 32;
  __shared__ u16 lA[4][256 * 32];   // 64KB
  __shared__ u16 lB[4][256 * 32];   // 64KB
  const int tid = threadIdx.x, lane = tid & 63, wid = tid >> 6;
  const int wr = wid >> 2, wc = wid & 3;

  const int nbx = gridDim.x;
  int bid = blockIdx.y * nbx + blockIdx.x;
  const int cpx = (nbx * gridDim.y) >> 3;
  bid = (bid & 7) * cpx + (bid >> 3);
  const int row0 = (bid / nbx) * 256, col0 = (bid % nbx) * 256;

  const int c0 = tid,       sr0 = c0 >> 2, q0 = ((c0 & 3) ^ (((sr0 >> 3) & 1) << 1)) * 8;
  const int c1 = tid + 512, sr1 = c1 >> 2, q1 = ((c1 & 3) ^ (((sr1 >> 3) & 1) << 1)) * 8;
  const u16* As0 = A  + (size_t)(row0 + sr0) * KK + q0;
  const u16* As1 = A  + (size_t)(row0 + sr1) * KK + q1;
  const u16* Bs0 = Bt + (size_t)(col0 + sr0) * KK + q0;
  const u16* Bs1 = Bt + (size_t)(col0 + sr1) * KK + q1;

  f32x4 acc[8][4] = {};
  const int lrow = lane & 15, kcol = (lane >> 4) * 8;

#pragma unroll
  for (int t = 0; t < 3; ++t) {
    load_lds16(As0 + t * 32, &lA[t][c0 * 8]);
    load_lds16(Bs0 + t * 32, &lB[t][c0 * 8]);
    load_lds16(As1 + t * 32, &lA[t][c1 * 8]);
    load_lds16(Bs1 + t * 32, &lB[t][c1 * 8]);
  }
  asm volatile("s_waitcnt vmcnt(8)" ::: "memory");
  __builtin_amdgcn_sched_barrier(0);
  __builtin_amdgcn_s_barrier();

#pragma unroll 4
  for (int j = 0; j < NK; ++j) {
    const int b = j & 3;
    const u16* la = lA[b];
    const u16* lb = lB[b];
    bf16x8 af[4], bfr[4];

    // ---------------- phase A: m 0..3
#pragma unroll
    for (int m = 0; m < 4; ++m) {
      const int row = wr * 128 + m * 16 + lrow;
      af[m] = *(const bf16x8*)&la[row * 32 + (kcol ^ (((row >> 3) & 1) << 4))];
    }
#pragma unroll
    for (int n = 0; n < 4; ++n) {
      const int row = wc * 64 + n * 16 + lrow;
      bfr[n] = *(const bf16x8*)&lb[row * 32 + (kcol ^ (((row >> 3) & 1) << 4))];
    }
    if (j + 3 < NK) {
      const int bb = (j + 3) & 3;
      load_lds16(As0 + (j + 3) * 32, &lA[bb][c0 * 8]);
      load_lds16(Bs0 + (j + 3) * 32, &lB[bb][c0 * 8]);
    }
    __builtin_amdgcn_s_setprio(1);
#pragma unroll
    for (int m = 0; m < 4; ++m)
#pragma unroll
      for (int n = 0; n < 4; ++n)
        acc[m][n] = __builtin_amdgcn_mfma_f32_16x16x32_bf16(af[m], bfr[n], acc[m][n], 0, 0, 0);
    __builtin_amdgcn_s_setprio(0);

    // ---------------- phase B: m 4..7 (bfr reused; no mid barrier)
#pragma unroll
    for (int m = 0; m < 4; ++m) {
      const int row = wr * 128 + (m + 4) * 16 + lrow;
      af[m] = *(const bf16x8*)&la[row * 32 + (kcol ^ (((row >> 3) & 1) << 4))];
    }
    if (j + 3 < NK) {
      const int bb = (j + 3) & 3;
      load_lds16(As1 + (j + 3) * 32, &lA[bb][c1 * 8]);
      load_lds16(Bs1 + (j + 3) * 32, &lB[bb][c1 * 8]);
    }
    __builtin_amdgcn_s_setprio(1);
#pragma unroll
    for (int m = 0; m < 4; ++m)
#pragma unroll
      for (int n = 0; n < 4; ++n)
        acc[m + 4][n] = __builtin_amdgcn_mfma_f32_16x16x32_bf16(af[m], bfr[n], acc[m + 4][n], 0, 0, 0);
    __builtin_amdgcn_s_setprio(0);
    if (j + 3 < NK)      { asm volatile("s_waitcnt vmcnt(8)" ::: "memory"); }
    else if (j + 2 < NK) { asm volatile("s_waitcnt vmcnt(4)" ::: "memory"); }
    else if (j + 1 < NK) { asm volatile("s_waitcnt vmcnt(0)" ::: "memory"); }
    __builtin_amdgcn_sched_barrier(0);
    __builtin_amdgcn_s_barrier();
  }

#pragma unroll
  for (int m = 0; m < 8; ++m)
#pragma unroll
    for (int n = 0; n < 4; ++n) {
      const int rbase = row0 + wr*128 + m*16 + ((lane >> 4) << 2);
      const int c     = col0 + wc*64 + n*16 + (lane & 15);
      float bv = 0.f;
      if (biasC)      bv = c < 1024 ? bias[c] * 0.125f
                         : (c < 2048 ? biasB[c - 1024] : biasC[c - 2048]);
      else if (bias)  bv = bias[c];
#pragma unroll
      for (int r = 0; r < 4; ++r) {
        float vv = acc[m][n][r] + bv;
        if (do_relu) vv = vv > 0.f ? vv : 0.f;
        store_out(&C[(size_t)(rbase + r) * N + c], vv);
      }
    }
}

// ----------------------------- GEMM 256x256 counted-vmcnt, split-K partial out
template <int KK>
__global__ __launch_bounds__(512, 1) void gemm256pk(
    const u16* __restrict__ A, const u16* __restrict__ Bt,
    u16* __restrict__ P, int M, int N, int Ktot)
{
  constexpr int NK = KK / 32;
  __shared__ u16 lA[4][256 * 32];
  __shared__ u16 lB[4][256 * 32];
  const int tid = threadIdx.x, lane = tid & 63, wid = tid >> 6;
  const int wr = wid >> 2, wc = wid & 3;

  const int nbx = gridDim.x;
  int bid = blockIdx.y * nbx + blockIdx.x;
  const int cpx = (nbx * gridDim.y) >> 3;
  bid = (bid & 7) * cpx + (bid >> 3);
  const int row0 = (bid / nbx) * 256, col0 = (bid % nbx) * 256;
  const int kb = blockIdx.z * KK;

  const int c0 = tid,       sr0 = c0 >> 2, q0 = ((c0 & 3) ^ (((sr0 >> 3) & 1) << 1)) * 8;
  const int c1 = tid + 512, sr1 = c1 >> 2, q1 = ((c1 & 3) ^ (((sr1 >> 3) & 1) << 1)) * 8;
  const u16* As0 = A  + (size_t)(row0 + sr0) * Ktot + kb + q0;
  const u16* As1 = A  + (size_t)(row0 + sr1) * Ktot + kb + q1;
  const u16* Bs0 = Bt + (size_t)(col0 + sr0) * Ktot + kb + q0;
  const u16* Bs1 = Bt + (size_t)(col0 + sr1) * Ktot + kb + q1;

  f32x4 acc[8][4] = {};
  const int lrow = lane & 15, kcol = (lane >> 4) * 8;

#pragma unroll
  for (int t = 0; t < 3; ++t) {
    load_lds16(As0 + t * 32, &lA[t][c0 * 8]);
    load_lds16(Bs0 + t * 32, &lB[t][c0 * 8]);
    load_lds16(As1 + t * 32, &lA[t][c1 * 8]);
    load_lds16(Bs1 + t * 32, &lB[t][c1 * 8]);
  }
  asm volatile("s_waitcnt vmcnt(8)" ::: "memory");
  __builtin_amdgcn_sched_barrier(0);
  __builtin_amdgcn_s_barrier();

#pragma unroll 4
  for (int j = 0; j < NK; ++j) {
    const int b = j & 3;
    const u16* la = lA[b];
    const u16* lb = lB[b];
    bf16x8 af[4], bfr[4];

#pragma unroll
    for (int m = 0; m < 4; ++m) {
      const int row = wr * 128 + m * 16 + lrow;
      af[m] = *(const bf16x8*)&la[row * 32 + (kcol ^ (((row >> 3) & 1) << 4))];
    }
#pragma unroll
    for (int n = 0; n < 4; ++n) {
      const int row = wc * 64 + n * 16 + lrow;
      bfr[n] = *(const bf16x8*)&lb[row * 32 + (kcol ^ (((row >> 3) & 1) << 4))];
    }
    if (j + 3 < NK) {
      const int bb = (j + 3) & 3;
      load_lds16(As0 + (j + 3) * 32, &lA[bb][c0 * 8]);
      load_lds16(Bs0 + (j + 3) * 32, &lB[bb][c0 * 8]);
    }
    __builtin_amdgcn_s_setprio(1);
#pragma unroll
    for (int m = 0; m < 4; ++m)
#pragma unroll
      for (int n = 0; n < 4; ++n)
        acc[m][n] = __builtin_amdgcn_mfma_f32_16x16x32_bf16(af[m], bfr[n], acc[m][n], 0, 0, 0);
    __builtin_amdgcn_s_setprio(0);

#pragma unroll
    for (int m = 0; m < 4; ++m) {
      const int row = wr * 128 + (m + 4) * 16 + lrow;
      af[m] = *(const bf16x8*)&la[row * 32 + (kcol ^ (((row >> 3) & 1) << 4))];
    }
    if (j + 3 < NK) {
      const int bb = (j + 3) & 3;
      load_lds16(As1 + (j + 3) * 32, &lA[bb][c1 * 8]);
      load_lds16(Bs1 + (j + 3) * 32, &lB[bb][c1 * 8]);
    }
    __builtin_amdgcn_s_setprio(1);
#pragma unroll
    for (int m = 0; m < 4; ++m)
#pragma unroll
      for (int n = 0; n < 4; ++n)
        acc[m + 4][n] = __builtin_amdgcn_mfma_f32_16x16x32_bf16(af[m], bfr[n], acc[m + 4][n], 0, 0, 0);
    __builtin_amdgcn_s_setprio(0);
    if (j + 3 < NK)      { asm volatile("s_waitcnt vmcnt(8)" ::: "memory"); }
    else if (j + 2 < NK) { asm volatile("s_waitcnt vmcnt(4)" ::: "memory"); }
    else if (j + 1 < NK) { asm volatile("s_waitcnt vmcnt(0)" ::: "memory"); }
    __builtin_amdgcn_sched_barrier(0);
    __builtin_amdgcn_s_barrier();
  }

  u16* Pz = P + (size_t)blockIdx.z * M * N;
#pragma unroll
  for (int m = 0; m < 8; ++m)
#pragma unroll
    for (int n = 0; n < 4; ++n) {
      const int rbase = row0 + wr*128 + m*16 + ((lane >> 4) << 2);
      const int c     = col0 + wc*64 + n*16 + (lane & 15);
#pragma unroll
      for (int r = 0; r < 4; ++r)
        Pz[(size_t)(rbase + r) * N + c] = f2bf(acc[m][n][r]);
    }
}

// ------------------------------------------- GEMM 128x64, 2-phase dbuf (proven)
template <typename OT>
__global__ __launch_bounds__(256) void gemm_bt64(
    const u16* __restrict__ A, const u16* __restrict__ Bt,
    const float* __restrict__ bias, const float* __restrict__ res,
    OT* __restrict__ C, int M, int N, int K, int do_relu)
{
  __shared__ u16 lA[2][128 * 32];
  __shared__ u16 lB[2][64 * 32];
  const int tid = threadIdx.x, lane = tid & 63, wid = tid >> 6;

  const int nbx = gridDim.x;
  int bid = blockIdx.y * nbx + blockIdx.x;
  const int cpx = (nbx * gridDim.y) >> 3;
  bid = (bid & 7) * cpx + (bid >> 3);
  const int row0 = (bid / nbx) * 128, col0 = (bid % nbx) * 64;

  f32x4 acc[2][4] = {};

  const int cc0 = tid, cc1 = tid + 256;
  const int r0 = cc0 >> 2, s0 = cc0 & 3;
  const int r1 = cc1 >> 2, s1 = cc1 & 3;
  const int ko0 = (s0 ^ ((r0 >> 1) & 3)) * 8;
  const int ko1 = (s1 ^ ((r1 >> 1) & 3)) * 8;

#define GST64(bf, k0)                                                         \
  {                                                                           \
    load_lds16(A  + (size_t)(row0 + r0) * K + (k0) + ko0, &lA[bf][cc0 * 8]);  \
    load_lds16(A  + (size_t)(row0 + r1) * K + (k0) + ko1, &lA[bf][cc1 * 8]);  \
    load_lds16(Bt + (size_t)(col0 + r0) * K + (k0) + ko0, &lB[bf][cc0 * 8]);  \
  }

  const int nk = K >> 5;
  GST64(0, 0);
  int cur = 0;
  for (int t = 0; t < nk; ++t) {
    __syncthreads();
    if (t + 1 < nk) GST64(cur ^ 1, (t + 1) * 32);
    bf16x8 af[2], bfr[4];
#pragma unroll
    for (int m = 0; m < 2; ++m) {
      const int row = wid * 32 + m * 16 + (lane & 15);
      af[m] = *(const bf16x8*)&lA[cur][row * 32 + (((lane >> 4) ^ ((row >> 1) & 3)) * 8)];
    }
#pragma unroll
    for (int n = 0; n < 4; ++n) {
      const int row = n * 16 + (lane & 15);
      bfr[n] = *(const bf16x8*)&lB[cur][row * 32 + (((lane >> 4) ^ ((row >> 1) & 3)) * 8)];
    }
#pragma unroll
    for (int m = 0; m < 2; ++m)
#pragma unroll
      for (int n = 0; n < 4; ++n)
        acc[m][n] = __builtin_amdgcn_mfma_f32_16x16x32_bf16(af[m], bfr[n], acc[m][n], 0, 0, 0);
    cur ^= 1;
  }
#undef GST64

#pragma unroll
  for (int m = 0; m < 2; ++m)
#pragma unroll
    for (int n = 0; n < 4; ++n) {
      const int rbase = row0 + wid*32 + m*16 + ((lane >> 4) << 2);
      const int c     = col0 + n*16 + (lane & 15);
      const float bv  = bias ? bias[c] : 0.f;
#pragma unroll
      for (int r = 0; r < 4; ++r) {
        const int rr = rbase + r;
        float vv = acc[m][n][r] + bv;
        if (res) vv += res[(size_t)rr * N + c];
        if (do_relu) vv = vv > 0.f ? vv : 0.f;
        store_out(&C[(size_t)rr * N + c], vv);
      }
    }
}

// ---------------------------- split-K=4 reduce: out = sum(bf16 partials)+x1+b2
__global__ __launch_bounds__(256) void ffr_reduce4(
    const u16* __restrict__ P, const float* __restrict__ x1,
    const float* __restrict__ b2, float* __restrict__ out)
{
  const size_t i = (size_t)blockIdx.x * 256 + threadIdx.x;   // float4 index
  const size_t M4 = (size_t)NT_ * D_;                        // elems per slab
  const float4 r  = ((const float4*)x1)[i];
  const float4 bb = ((const float4*)b2)[i & 255];
  float o0 = r.x + bb.x, o1 = r.y + bb.y, o2 = r.z + bb.z, o3 = r.w + bb.w;
#pragma unroll
  for (int z = 0; z < 4; ++z) {
    const u16x4 p = *(const u16x4*)(P + z * M4 + i * 4);
    o0 += bf2f(p[0]); o1 += bf2f(p[1]); o2 += bf2f(p[2]); o3 += bf2f(p[3]);
  }
  float4 o; o.x = o0; o.y = o1; o.z = o2; o.w = o3;
  ((float4*)out)[i] = o;
}

// ------------------------------------------------------------ flash attention
// Round-13 proven version: 512 thr / 8 waves, 128 q-rows/block, KVBLK=64,
// 1-D XCD-chunked grid (each XCD owns 4 complete (b,h) K/V panels).
__global__ __launch_bounds__(512) void attn_kernel(
    const u16* __restrict__ QKV, const u16* __restrict__ Kt,
    const u16* __restrict__ Vt, u16* __restrict__ O)
{
  __shared__ u16 lK[2][64 * 64];
  __shared__ u16 lV[2][64 * 64];
  __shared__ u16 lP[128 * 64];

  const int tid = threadIdx.x, lane = tid & 63, wid = tid >> 6;   // wid 0..7
  const int g  = (blockIdx.x & 7) * 64 + (blockIdx.x >> 3);       // 0..511
  const int qt = g & 15, h = (g >> 4) & 15, b = g >> 8;
  const int z  = b * H_ + h;

  const u16* Qp  = QKV + (size_t)(b * S_ + qt * 128) * QS_ + h * DK_;
  const u16* Kpb = Kt + (size_t)z * S_ * 64;       // packed: tile = 8KB contiguous
  const u16* Vb  = Vt + (size_t)z * DK_ * S_;

  bf16x8 qf[2];
  {
    const int qr = wid * 16 + (lane & 15);    // 0..127
    qf[0] = *(const bf16x8*)(Qp + (size_t)qr * QS_ + (lane >> 4) * 8);
    qf[1] = *(const bf16x8*)(Qp + (size_t)qr * QS_ + 32 + (lane >> 4) * 8);
  }

  const bf16x8 vone = {16256,16256,16256,16256,16256,16256,16256,16256}; // bf16 1.0

#define STAGE_KV(bf, kt_)                                                     \
  {                                                                           \
    const u16* Kp = Kpb + (size_t)(kt_) * 64 * 64;                            \
    const u16* Vp = Vb + (size_t)(kt_) * 64;                                  \
    const int c = tid, r = c >> 3, sub = c & 7;                               \
    load_lds16(Kp + r * 64 + ((sub ^ (r & 7)) * 8), &lK[bf][c * 8]);          \
    load_lds16(Vp + (size_t)r * S_ + ((sub ^ (r & 7)) * 8), &lV[bf][c * 8]);  \
  }

  float m_run = -1e30f;
  f32x4 l_acc = {};
  f32x4 o_acc[4] = {};

  STAGE_KV(0, 0);
  int cur = 0;

  for (int kt = 0; kt < S_ / 64; ++kt) {
    __syncthreads();                       // stage(cur) done; prev PV done
    if (kt + 1 < S_ / 64) STAGE_KV(cur ^ 1, kt + 1);

    f32x4 s[4];
    __builtin_amdgcn_s_setprio(1);
#pragma unroll
    for (int kf = 0; kf < 4; ++kf) {
      const int row = kf * 16 + (lane & 15);
      const int i0 = (row * 64 + (lane >> 4) * 8)      ^ ((row & 7) << 3);
      const int i1 = (row * 64 + 32 + (lane >> 4) * 8) ^ ((row & 7) << 3);
      bf16x8 k0 = *(const bf16x8*)&lK[cur][i0];
      bf16x8 k1 = *(const bf16x8*)&lK[cur][i1];
      f32x4 sc = {};
      sc = __builtin_amdgcn_mfma_f32_16x16x32_bf16(k0, qf[0], sc, 0, 0, 0);
      sc = __builtin_amdgcn_mfma_f32_16x16x32_bf16(k1, qf[1], sc, 0, 0, 0);
      s[kf] = sc;
    }
    __builtin_amdgcn_s_setprio(0);

    float t0 = fmaxf(fmaxf(s[0][0], s[0][1]), fmaxf(s[0][2], s[0][3]));
    float t1 = fmaxf(fmaxf(s[1][0], s[1][1]), fmaxf(s[1][2], s[1][3]));
    float t2 = fmaxf(fmaxf(s[2][0], s[2][1]), fmaxf(s[2][2], s[2][3]));
    float t3 = fmaxf(fmaxf(s[3][0], s[3][1]), fmaxf(s[3][2], s[3][3]));
    float pmax = fmaxf(fmaxf(t0, t1), fmaxf(t2, t3));
    pmax = fmaxf(pmax, __shfl_xor(pmax, 16));
    pmax = fmaxf(pmax, __shfl_xor(pmax, 32));

    const bool grow = pmax > m_run + 8.0f;
    const float mnew = grow ? pmax : m_run;
    if (__any(grow)) {
      const float scale = __expf(m_run - mnew);
#pragma unroll
      for (int r = 0; r < 4; ++r) {
        const float sr = __shfl(scale, (lane >> 4) * 4 + r);
        l_acc[r] *= sr;
#pragma unroll
        for (int nf = 0; nf < 4; ++nf) o_acc[nf][r] *= sr;
      }
    }
    m_run = mnew;

    const int prow = wid * 16 + (lane & 15);     // 0..127
#pragma unroll
    for (int kf = 0; kf < 4; ++kf) {
      u16x4 pk;
#pragma unroll
      for (int r = 0; r < 4; ++r) pk[r] = f2bf_up(__expf(s[kf][r] - m_run));
      const int idx = (prow * 64 + kf * 16 + (lane >> 4) * 4) ^ ((prow & 7) << 3);
      *(u16x4*)&lP[idx] = pk;
    }
    asm volatile("s_waitcnt lgkmcnt(0)" ::: "memory");   // wave-local RAW fence
    __builtin_amdgcn_sched_barrier(0);

    bf16x8 pa0 = *(const bf16x8*)&lP[(prow * 64 + (lane >> 4) * 8)      ^ ((prow & 7) << 3)];
    bf16x8 pa1 = *(const bf16x8*)&lP[(prow * 64 + 32 + (lane >> 4) * 8) ^ ((prow & 7) << 3)];
    __builtin_amdgcn_s_setprio(1);
    l_acc = __builtin_amdgcn_mfma_f32_16x16x32_bf16(pa0, vone, l_acc, 0, 0, 0);
    l_acc = __builtin_amdgcn_mfma_f32_16x16x32_bf16(pa1, vone, l_acc, 0, 0, 0);
#pragma unroll
    for (int nf = 0; nf < 4; ++nf) {
      const int vrow = nf * 16 + (lane & 15);
      bf16x8 v0 = *(const bf16x8*)&lV[cur][(vrow * 64 + (lane >> 4) * 8)      ^ ((vrow & 7) << 3)];
      bf16x8 v1 = *(const bf16x8*)&lV[cur][(vrow * 64 + 32 + (lane >> 4) * 8) ^ ((vrow & 7) << 3)];
      o_acc[nf] = __builtin_amdgcn_mfma_f32_16x16x32_bf16(pa0, v0, o_acc[nf], 0, 0, 0);
      o_acc[nf] = __builtin_amdgcn_mfma_f32_16x16x32_bf16(pa1, v1, o_acc[nf], 0, 0, 0);
    }
    __builtin_amdgcn_s_setprio(0);
    cur ^= 1;
  }

#pragma unroll
  for (int nf = 0; nf < 4; ++nf)
#pragma unroll
    for (int r = 0; r < 4; ++r) {
      const int qrow = qt * 128 + wid * 16 + (lane >> 4) * 4 + r;
      const int col  = h * DK_ + nf * 16 + (lane & 15);
      O[(size_t)(b * S_ + qrow) * D_ + col] = f2bf(o_acc[nf][r] / l_acc[r]);
    }
}

// ------------------------------------------------------------------ launcher
extern "C" void kernel_launch(void* const* d_in, const int* in_sizes, int n_in,
                              void* d_out, int out_size, void* d_ws, size_t ws_size,
                              hipStream_t stream)
{
  const float* x   = (const float*)d_in[0];
  const float* Wq  = (const float*)d_in[1];
  const float* bq  = (const float*)d_in[2];
  const float* Wk  = (const float*)d_in[3];
  const float* bk  = (const float*)d_in[4];
  const float* Wv  = (const float*)d_in[5];
  const float* bv  = (const float*)d_in[6];
  const float* Wo  = (const float*)d_in[7];
  const float* bo  = (const float*)d_in[8];
  const float* W1  = (const float*)d_in[9];
  const float* b1  = (const float*)d_in[10];
  const float* W2  = (const float*)d_in[11];
  const float* b2  = (const float*)d_in[12];
  const float* g1  = (const float*)d_in[13];
  const float* be1 = (const float*)d_in[14];
  const float* g2  = (const float*)d_in[15];
  const float* be2 = (const float*)d_in[16];
  float* out = (float*)d_out;

  const size_t MB = 1024 * 1024;
  char* base = (char*)d_ws;
  u16*   xn    = (u16*)(base);             //  8MB bf16 [4096][1024]
  u16*   qkv   = (u16*)(base +  8*MB);     // 24MB bf16 [4096][3072]
  u16*   ctx   = (u16*)(base + 32*MB);     //  8MB bf16 [4096][1024]
  float* x1    = (float*)(base + 40*MB);   // 16MB f32  [4096][1024]
  u16*   vt    = (u16*)(base + 40*MB);     //  8MB bf16 [32][64][2048] (dead before x1)
  u16*   kt    = (u16*)(base + 48*MB);     //  8MB bf16 [32][2048][64] (dead before x1)
  u16*   ff1   = (u16*)(base +  8*MB);     // 32MB bf16 [4096][4096] (reuses qkv+ctx)
  u16*   wqkvT = (u16*)(base + 56*MB);     //  6MB
  u16*   woT   = (u16*)(base + 62*MB);     //  2MB
  u16*   w1T   = (u16*)(base + 64*MB);     //  8MB
  u16*   w2T   = (u16*)(base + 72*MB);     //  8MB
  u16*   pkh   = (u16*)(base + 80*MB);     // 32MB bf16 split-K partials [4][4096][1024]

  const bool splitk = ws_size >= (size_t)112 * MB;

  dim3 blk(256);
  transpose_qkv<<<dim3(2, 32, 48), blk, 0, stream>>>(Wq, Wk, Wv, wqkvT);
  transpose_w<<<dim3(9216), blk, 0, stream>>>(Wo, W1, W2, woT, w1T, w2T);

  ln_kernel<<<NT_, blk, 0, stream>>>(x, g1, be1, xn);

  // fused QKV projection via 256x256 counted-vmcnt kernel (192 blocks)
  gemm256<u16, 1024><<<dim3(12, 16), dim3(512), 0, stream>>>(
      xn, wqkvT, bq, bk, bv, qkv, NT_, QS_, 0);

  pack_kv<<<dim3(S_ / 32, B_ * H_), blk, 0, stream>>>(qkv, kt, vt);

  attn_kernel<<<dim3(512), dim3(512), 0, stream>>>(qkv, kt, vt, ctx);

  gemm_bt64<<<dim3(16, 32), blk, 0, stream>>>(ctx, woT, bo, x, x1, NT_, D_, D_, 0);

  ln_kernel<<<NT_, blk, 0, stream>>>(x1, g2, be2, xn);

  // FF1 via 256x256 counted-vmcnt kernel (256 blocks)
  gemm256<u16, 1024><<<dim3(16, 16), dim3(512), 0, stream>>>(
      xn, w1T, b1, (const float*)nullptr, (const float*)nullptr, ff1, NT_, DFF_, 1);

  if (splitk) {
    // FF2 via gemm256 template, split-K=4 (4x64 = 256 blocks, KK=1024)
    gemm256pk<1024><<<dim3(4, 16, 4), dim3(512), 0, stream>>>(
        ff1, w2T, pkh, NT_, D_, DFF_);
    ffr_reduce4<<<dim3(4096), blk, 0, stream>>>(pkh, x1, b2, out);
  } else {
    gemm_bt64<<<dim3(16, 32), blk, 0, stream>>>(ff1, w2T, b2, x1, out, NT_, D_, DFF_, 0);
  }
}